// Round 1
// 198.958 us; speedup vs baseline: 1.0013x; 1.0013x over previous
//
#include <hip/hip_runtime.h>

// ---------------------------------------------------------------------------
// QuantumQKGenerator: out[b, 0..9]=<X_q>, [10..19]=<Y_q>, [20..29]=<Z_q> of
// state S = QFT * U_circuit * normalize(x[b]).  Since x is real and the
// circuit+QFT is a fixed unitary W (depends only on the 40 weights), we:
//   1) prep: build W rows by basis-state sim + FFT  AND  normalize x -> fp16
//   2) transpose W to K-contiguous layout for MFMA
//   3) S = Xn @ W  as one fp16 MFMA GEMM  M=8192 N=2048(re/im) K=1024
//   4) expect: per-wave row reduction, 17KB LDS, zero barriers
// ---------------------------------------------------------------------------

typedef _Float16 half8_t __attribute__((ext_vector_type(8)));
typedef _Float16 half4_t __attribute__((ext_vector_type(4)));
typedef float floatx4 __attribute__((ext_vector_type(4)));

#define GLB_CAST(p) ((const __attribute__((address_space(1))) void*)(p))
#define LDS_CAST(p) ((__attribute__((address_space(3))) void*)(p))

// ---------------------------------------------------------------------------
// Kernel 1: blocks [0,1024): simulate circuit on basis |jb>, FFT, emit W row.
//           blocks [1024,9216): row-normalize x -> fp16 Xh.
// Wire q <-> bit position (9-q)  (wire 0 = MSB).
// ---------------------------------------------------------------------------
__global__ __launch_bounds__(256) void prep_kernel(const float* __restrict__ w,
                                                   const float* __restrict__ x,
                                                   _Float16* __restrict__ Wh,
                                                   _Float16* __restrict__ Xh)
{
    __shared__ float smem[2048 + 88];   // sr[1024] | si[1024] | wc[40] | wsn[40] | wsum[4]
    const int tid = threadIdx.x;

    if (blockIdx.x >= 1024) {
        // ---------------- normalize path ----------------
        float* wsum = smem;
        const int b = blockIdx.x - 1024;
        float4 v = ((const float4*)(x + (size_t)b * 1024))[tid];
        float ss = v.x*v.x + v.y*v.y + v.z*v.z + v.w*v.w;
        #pragma unroll
        for (int off = 32; off; off >>= 1) ss += __shfl_down(ss, off);
        if ((tid & 63) == 0) wsum[tid >> 6] = ss;
        __syncthreads();
        float scale = 1.0f / fmaxf(sqrtf(wsum[0] + wsum[1] + wsum[2] + wsum[3]), 1e-8f);
        half4_t h;
        h[0] = (_Float16)(v.x * scale);
        h[1] = (_Float16)(v.y * scale);
        h[2] = (_Float16)(v.z * scale);
        h[3] = (_Float16)(v.w * scale);
        ((half4_t*)(Xh + (size_t)b * 1024))[tid] = h;
        return;
    }

    // ---------------- build_w path ----------------
    float* sr  = smem;
    float* si  = smem + 1024;
    float* wc  = smem + 2048;
    float* wsn = smem + 2088;
    const int jb = blockIdx.x;

    if (tid < 40) {
        float t = w[tid] * 0.5f;
        wc[tid]  = cosf(t);
        wsn[tid] = sinf(t);
    }
    for (int i = tid; i < 1024; i += 256) { sr[i] = (i == jb) ? 1.0f : 0.0f; si[i] = 0.0f; }
    __syncthreads();

    // layers: 0=RX(w0), 1=RY(w1), 2=RZ(w2), [CNOT ring], 3=RY(w3)
    for (int layer = 0; layer < 4; ++layer) {
        if (layer == 3) {
            // CNOT ring: control q, target (q+1)%10
            for (int q = 0; q < 10; ++q) {
                int mc = 1 << (9 - q);
                int mt = 1 << (9 - ((q + 1) % 10));
                for (int p = tid; p < 512; p += 256) {
                    int i0 = ((p & ~(mt - 1)) << 1) | (p & (mt - 1)); // target bit = 0
                    if (i0 & mc) {
                        int i1 = i0 | mt;
                        float tr = sr[i0]; sr[i0] = sr[i1]; sr[i1] = tr;
                        float ti = si[i0]; si[i0] = si[i1]; si[i1] = ti;
                    }
                }
                __syncthreads();
            }
        }
        int wi = (layer == 3) ? 3 : layer;
        for (int q = 0; q < 10; ++q) {
            float c = wc[q * 4 + wi], s = wsn[q * 4 + wi];
            float u00r, u00i, u01r, u01i, u10r, u10i, u11r, u11i;
            if (layer == 0) {        // RX = [[c, -i s],[-i s, c]]
                u00r=c; u00i=0; u01r=0; u01i=-s; u10r=0; u10i=-s; u11r=c; u11i=0;
            } else if (layer == 2) { // RZ = [[e^{-it/2},0],[0,e^{+it/2}]]
                u00r=c; u00i=-s; u01r=0; u01i=0; u10r=0; u10i=0; u11r=c; u11i=s;
            } else {                 // RY = [[c,-s],[s,c]]
                u00r=c; u00i=0; u01r=-s; u01i=0; u10r=s; u10i=0; u11r=c; u11i=0;
            }
            int m = 1 << (9 - q);
            for (int p = tid; p < 512; p += 256) {
                int i0 = ((p & ~(m - 1)) << 1) | (p & (m - 1));
                int i1 = i0 | m;
                float ar = sr[i0], ai = si[i0], br = sr[i1], bi = si[i1];
                sr[i0] = u00r*ar - u00i*ai + u01r*br - u01i*bi;
                si[i0] = u00r*ai + u00i*ar + u01r*bi + u01i*br;
                sr[i1] = u10r*ar - u10i*ai + u11r*br - u11i*bi;
                si[i1] = u10r*ai + u10i*ar + u11r*bi + u11i*br;
            }
            __syncthreads();
        }
    }

    // QFT_MAT[j,k] = exp(+2*pi*i*j*k/1024)/32 -> radix-2 DIT FFT (+i twiddles)
    for (int i = tid; i < 1024; i += 256) {
        int r = (int)(__brev((unsigned)i) >> 22);
        if (r > i) {
            float tr = sr[i]; sr[i] = sr[r]; sr[r] = tr;
            float ti = si[i]; si[i] = si[r]; si[r] = ti;
        }
    }
    __syncthreads();
    for (int st = 1; st <= 10; ++st) {
        int hf = 1 << (st - 1);
        float astep = 6.28318530717958647f / (float)(1 << st);
        for (int p = tid; p < 512; p += 256) {
            int j2 = p & (hf - 1);
            int i0 = ((p >> (st - 1)) << st) | j2;
            int i1 = i0 + hf;
            float ang = astep * (float)j2;
            float sw, cw;
            __sincosf(ang, &sw, &cw);
            float br2 = sr[i1], bi2 = si[i1];
            float tr = cw*br2 - sw*bi2;
            float ti = cw*bi2 + sw*br2;
            float ur = sr[i0], ui = si[i0];
            sr[i0] = ur + tr; si[i0] = ui + ti;
            sr[i1] = ur - tr; si[i1] = ui - ti;
        }
        __syncthreads();
    }
    for (int k = tid; k < 1024; k += 256) {
        Wh[(size_t)jb * 2048 + 2*k]     = (_Float16)(sr[k] * 0.03125f);
        Wh[(size_t)jb * 2048 + 2*k + 1] = (_Float16)(si[k] * 0.03125f);
    }
}

// ---------------------------------------------------------------------------
// Kernel 1b: Bt[n][j] = Wh[j][n]   ([2048][1024] fp16, K-contiguous rows)
// ---------------------------------------------------------------------------
__global__ __launch_bounds__(256) void transpose_kernel(const _Float16* __restrict__ Wh,
                                                        _Float16* __restrict__ Bt)
{
    __shared__ _Float16 tile[32][33];
    const int bx = blockIdx.x;   // n tile (64)
    const int by = blockIdx.y;   // j tile (32)
    const int tx = threadIdx.x;  // 32
    const int ty = threadIdx.y;  // 8
    #pragma unroll
    for (int i = 0; i < 4; ++i) {
        int r = ty + 8*i;
        tile[r][tx] = Wh[(size_t)(by*32 + r) * 2048 + bx*32 + tx];
    }
    __syncthreads();
    #pragma unroll
    for (int i = 0; i < 4; ++i) {
        int r = ty + 8*i;
        Bt[(size_t)(bx*32 + r) * 1024 + by*32 + tx] = tile[tx][r];
    }
}

// ---------------------------------------------------------------------------
// Kernel 2: GEMM  Sh[8192][2048] = Xh[8192][1024] * Bt^T  (fp16 in, fp32 acc,
// fp16 out).  128x128 tile, BK=64 (16 k-iters), global_load_lds width 16,
// XOR-swizzled LDS (swizzle applied on the global-address side to keep the
// wave-uniform base + 16B*lane layout global_load_lds requires).
// ---------------------------------------------------------------------------
__global__ __launch_bounds__(256, 2) void gemm_kernel(const _Float16* __restrict__ A,
                                                      const _Float16* __restrict__ Bt,
                                                      _Float16* __restrict__ C)
{
    __shared__ __align__(16) _Float16 As[128][64];
    __shared__ __align__(16) _Float16 Bs[128][64];
    const int tid  = threadIdx.x;
    const int wave = tid >> 6;
    const int lane = tid & 63;
    const int m0 = blockIdx.y * 128;
    const int n0 = blockIdx.x * 128;

    // staging: wave w, instr t covers rows 32w+8t .. 32w+8t+7.
    // lane l -> row offset (l>>3), global k-chunk ((l&7) ^ (l>>3))  [swizzle]
    const int srow = lane >> 3;                 // 0..7
    const int schk = (lane & 7) ^ srow;         // swizzled chunk
    const _Float16* gA = A  + (size_t)(m0 + 32*wave + srow) * 1024 + schk * 8;
    const _Float16* gB = Bt + (size_t)(n0 + 32*wave + srow) * 1024 + schk * 8;
    _Float16* lA = &As[0][0] + wave*2048 + lane*8;
    _Float16* lB = &Bs[0][0] + wave*2048 + lane*8;

    // fragment indexing (verified layouts: A row=lane&15, k=(lane>>4)*8+j;
    // C/D col=lane&15, row=(lane>>4)*4+reg)
    const int fr = lane & 15;
    const int fc = lane >> 4;
    const int sx = fr & 7;          // de-swizzle constant for fragment reads
    const int wm = (wave >> 1) * 64;
    const int wn = (wave & 1) * 64;

    floatx4 acc[4][4];
    #pragma unroll
    for (int i = 0; i < 4; ++i)
        #pragma unroll
        for (int j = 0; j < 4; ++j)
            acc[i][j] = (floatx4){0.f, 0.f, 0.f, 0.f};

    for (int kt = 0; kt < 16; ++kt) {
        #pragma unroll
        for (int t = 0; t < 4; ++t) {
            __builtin_amdgcn_global_load_lds(GLB_CAST(gA + (size_t)t*8*1024), LDS_CAST(lA + t*512), 16, 0, 0);
            __builtin_amdgcn_global_load_lds(GLB_CAST(gB + (size_t)t*8*1024), LDS_CAST(lB + t*512), 16, 0, 0);
        }
        gA += 64; gB += 64;
        __syncthreads();
        #pragma unroll
        for (int kh = 0; kh < 2; ++kh) {
            half8_t af[4], bf[4];
            #pragma unroll
            for (int i = 0; i < 4; ++i)
                af[i] = *(const half8_t*)&As[wm + i*16 + fr][((kh*4 + fc) ^ sx) * 8];
            #pragma unroll
            for (int i = 0; i < 4; ++i)
                bf[i] = *(const half8_t*)&Bs[wn + i*16 + fr][((kh*4 + fc) ^ sx) * 8];
            #pragma unroll
            for (int mi = 0; mi < 4; ++mi)
                #pragma unroll
                for (int ni = 0; ni < 4; ++ni)
                    acc[mi][ni] = __builtin_amdgcn_mfma_f32_16x16x32_f16(af[mi], bf[ni], acc[mi][ni], 0, 0, 0);
        }
        __syncthreads();
    }

    #pragma unroll
    for (int mi = 0; mi < 4; ++mi) {
        #pragma unroll
        for (int r = 0; r < 4; ++r) {
            int row = m0 + wm + mi*16 + fc*4 + r;
            _Float16* cp = C + (size_t)row * 2048 + n0 + wn + fr;
            #pragma unroll
            for (int ni = 0; ni < 4; ++ni)
                cp[ni*16] = (_Float16)acc[mi][ni][r];
        }
    }
}

// ---------------------------------------------------------------------------
// Kernel 3: expectations from S.  One WAVE per batch row; lane l owns the 16
// complex amps k = l*16 + i in registers.
//   k-bits 0..3  (qubits 9..6): intra-lane pairs, pure register math.
//   k-bits 4..9  (qubits 5..0): lane-XOR {1,2,4,8,16,32}; partner chunk
//     fetched from a 16B-XOR-swizzled wave-private LDS copy of the row.
//   Reduction: LDS transpose reusing the SAME LDS region.  Zero barriers.
//
// R3 fix: the cross-lane loop previously indexed c[] with a RUNTIME index
// (ju = j0 + j, j0 = mybit ? 4 : 0).  Rule: runtime-indexed register arrays
// are demoted to scratch -- rocprof showed WRITE_SIZE 66.6 MB (= 32 floats
// x 524288 threads spilled) vs the 1 MB output, VGPR_Count=52, kernel
// scratch-bound at 51 us.  Fix: select operand VALUES with mybit (cndmask),
// keep every c[] index compile-time.  j0 remains only in the LDS address
// (memory, not a register array -- harmless).
// ---------------------------------------------------------------------------
__global__ __launch_bounds__(128, 4) void expect_kernel(const _Float16* __restrict__ Sh,
                                                        float* __restrict__ out)
{
    __shared__ __align__(16) float buf[2][2176];   // per-wave: row(2048) / pt(2112) alias
    const int tid = threadIdx.x;
    const int w = tid >> 6, l = tid & 63;
    const int row = blockIdx.x * 2 + w;
    float* bw = buf[w];

    // ---- load own 16 complex amps (64B contiguous per lane) -> registers
    const _Float16* src = Sh + (size_t)row * 2048 + l * 32;
    float2 c[16];
    #pragma unroll
    for (int t = 0; t < 4; ++t) {
        half8_t v = ((const half8_t*)src)[t];
        #pragma unroll
        for (int u = 0; u < 4; ++u)
            c[t*4 + u] = make_float2((float)v[2*u], (float)v[2*u + 1]);
    }

    // ---- stage to swizzled LDS: unit j (2 complex) at slot l*8 + (j ^ (l&7))
    #pragma unroll
    for (int j = 0; j < 8; ++j) {
        int su = l*8 + (j ^ (l & 7));
        ((float4*)bw)[su] = make_float4(c[2*j].x, c[2*j].y, c[2*j+1].x, c[2*j+1].y);
    }

    float P2s = 0.f;
    #pragma unroll
    for (int i = 0; i < 16; ++i)
        P2s += c[i].x*c[i].x + c[i].y*c[i].y;

    float cr[10], ci[10], cz[10];
    #pragma unroll
    for (int q = 0; q < 10; ++q) { cr[q] = 0.f; ci[q] = 0.f; cz[q] = 0.f; }

    // intra-lane qubits: k-bit p = 0..3  ->  q = 9-p   (|c|^2 recomputed
    // inline instead of a p2[16] array: -16 live VGPRs)
    #pragma unroll
    for (int p = 0; p < 4; ++p) {
        const int m = 1 << p;
        const int q = 9 - p;
        #pragma unroll
        for (int i = 0; i < 16; ++i) {
            if (i & m) continue;
            const int j = i | m;
            cr[q] += c[i].x*c[j].x + c[i].y*c[j].y;
            ci[q] += c[i].x*c[j].y - c[i].y*c[j].x;
            cz[q] += (c[i].x*c[i].x + c[i].y*c[i].y) - (c[j].x*c[j].x + c[j].y*c[j].y);
        }
    }

    // cross-lane qubits: lane-bit e (k-bit 4+e) -> q = 5-e
    // (wave-internal LDS ordering: no barrier needed)
    #pragma unroll
    for (int e = 0; e < 6; ++e) {
        const int q = 5 - e;
        const int part = l ^ (1 << e);
        const int mybit = (l >> e) & 1;
        const float sgn = mybit ? -1.f : 1.f;
        const int j0 = mybit ? 4 : 0;   // my half of the pair's units (LDS addr only)
        float rr = 0.f, ii = 0.f;
        #pragma unroll
        for (int j = 0; j < 4; ++j) {
            const int su = part*8 + ((j0 + j) ^ (part & 7));
            float4 f = ((const float4*)bw)[su];
            // own amps: unit j (mybit=0 half) vs unit j+4 (mybit=1 half),
            // selected by VALUE so c[] indices stay compile-time constant.
            const float2 a0 = c[2*j],     a1 = c[2*j + 1];
            const float2 b0 = c[2*j + 8], b1 = c[2*j + 9];
            const float m0x = mybit ? b0.x : a0.x;
            const float m0y = mybit ? b0.y : a0.y;
            const float m1x = mybit ? b1.x : a1.x;
            const float m1y = mybit ? b1.y : a1.y;
            rr += m0x*f.x + m0y*f.y;
            ii += m0x*f.y - m0y*f.x;
            rr += m1x*f.z + m1y*f.w;
            ii += m1x*f.w - m1y*f.z;
        }
        cr[q] += rr;
        ci[q] += sgn * ii;
        cz[q] += sgn * P2s;
    }

    // ---- reduction: transpose through the SAME LDS region (row buffer dead)
    #pragma unroll
    for (int q = 0; q < 10; ++q) {
        bw[l*33 + q]      = cr[q];
        bw[l*33 + 10 + q] = ci[q];
        bw[l*33 + 20 + q] = cz[q];
    }

    if (l < 60) {
        const int o = (l < 30) ? l : l - 30;
        const int h = (l < 30) ? 0 : 32;
        float s = 0.f;
        #pragma unroll
        for (int jj = 0; jj < 32; ++jj)
            s += bw[(h + jj)*33 + o];
        float s2 = __shfl(s, (l < 30) ? (l + 30) : (l - 30));
        if (l < 30) {
            float v = s + s2;
            if (o < 20) v *= 2.0f;
            out[(size_t)row * 30 + o] = v;
        }
    }
}

// ---------------------------------------------------------------------------
extern "C" void kernel_launch(void* const* d_in, const int* in_sizes, int n_in,
                              void* d_out, int out_size, void* d_ws, size_t ws_size,
                              hipStream_t stream) {
    const float* x = (const float*)d_in[0];   // [8192][1024]
    const float* w = (const float*)d_in[1];   // [10][4]
    float* out = (float*)d_out;               // [8192][30]
    char* ws = (char*)d_ws;
    // workspace layout (56 MB total):
    _Float16* Wh = (_Float16*)(ws);                         //  4 MB [1024][2048]
    _Float16* Bt = (_Float16*)(ws + ((size_t)4  << 20));    //  4 MB [2048][1024]
    _Float16* Xh = (_Float16*)(ws + ((size_t)8  << 20));    // 16 MB [8192][1024]
    _Float16* Sh = (_Float16*)(ws + ((size_t)24 << 20));    // 32 MB [8192][2048]

    prep_kernel<<<9216, 256, 0, stream>>>(w, x, Wh, Xh);
    transpose_kernel<<<dim3(64, 32), dim3(32, 8), 0, stream>>>(Wh, Bt);
    gemm_kernel<<<dim3(16, 64), 256, 0, stream>>>(Xh, Bt, Sh);
    expect_kernel<<<4096, 128, 0, stream>>>(Sh, out);
}

// Round 2
// 172.103 us; speedup vs baseline: 1.1576x; 1.1560x over previous
//
#include <hip/hip_runtime.h>

// ---------------------------------------------------------------------------
// QuantumQKGenerator: out[b, 0..9]=<X_q>, [10..19]=<Y_q>, [20..29]=<Z_q> of
// state S = QFT * U_circuit * normalize(x[b]).  Since x is real and the
// circuit+QFT is a fixed unitary W (depends only on the 40 weights), we:
//   1) prep: build W rows by basis-state sim + FFT  AND  normalize x -> fp16
//   2) transpose W to K-contiguous layout for MFMA
//   3) S = Xn @ W  as one fp16 MFMA GEMM  M=8192 N=2048(re/im) K=1024
//   4) expect: per-wave row reduction, butterfly wave-sums, minimal VGPR state
// ---------------------------------------------------------------------------

typedef _Float16 half8_t __attribute__((ext_vector_type(8)));
typedef _Float16 half4_t __attribute__((ext_vector_type(4)));
typedef float floatx4 __attribute__((ext_vector_type(4)));

#define GLB_CAST(p) ((const __attribute__((address_space(1))) void*)(p))
#define LDS_CAST(p) ((__attribute__((address_space(3))) void*)(p))

// ---------------------------------------------------------------------------
// Kernel 1: blocks [0,1024): simulate circuit on basis |jb>, FFT, emit W row.
//           blocks [1024,9216): row-normalize x -> fp16 Xh.
// Wire q <-> bit position (9-q)  (wire 0 = MSB).
// ---------------------------------------------------------------------------
__global__ __launch_bounds__(256) void prep_kernel(const float* __restrict__ w,
                                                   const float* __restrict__ x,
                                                   _Float16* __restrict__ Wh,
                                                   _Float16* __restrict__ Xh)
{
    __shared__ float smem[2048 + 88];   // sr[1024] | si[1024] | wc[40] | wsn[40] | wsum[4]
    const int tid = threadIdx.x;

    if (blockIdx.x >= 1024) {
        // ---------------- normalize path ----------------
        float* wsum = smem;
        const int b = blockIdx.x - 1024;
        float4 v = ((const float4*)(x + (size_t)b * 1024))[tid];
        float ss = v.x*v.x + v.y*v.y + v.z*v.z + v.w*v.w;
        #pragma unroll
        for (int off = 32; off; off >>= 1) ss += __shfl_down(ss, off);
        if ((tid & 63) == 0) wsum[tid >> 6] = ss;
        __syncthreads();
        float scale = 1.0f / fmaxf(sqrtf(wsum[0] + wsum[1] + wsum[2] + wsum[3]), 1e-8f);
        half4_t h;
        h[0] = (_Float16)(v.x * scale);
        h[1] = (_Float16)(v.y * scale);
        h[2] = (_Float16)(v.z * scale);
        h[3] = (_Float16)(v.w * scale);
        ((half4_t*)(Xh + (size_t)b * 1024))[tid] = h;
        return;
    }

    // ---------------- build_w path ----------------
    float* sr  = smem;
    float* si  = smem + 1024;
    float* wc  = smem + 2048;
    float* wsn = smem + 2088;
    const int jb = blockIdx.x;

    if (tid < 40) {
        float t = w[tid] * 0.5f;
        wc[tid]  = cosf(t);
        wsn[tid] = sinf(t);
    }
    for (int i = tid; i < 1024; i += 256) { sr[i] = (i == jb) ? 1.0f : 0.0f; si[i] = 0.0f; }
    __syncthreads();

    // layers: 0=RX(w0), 1=RY(w1), 2=RZ(w2), [CNOT ring], 3=RY(w3)
    for (int layer = 0; layer < 4; ++layer) {
        if (layer == 3) {
            // CNOT ring: control q, target (q+1)%10
            for (int q = 0; q < 10; ++q) {
                int mc = 1 << (9 - q);
                int mt = 1 << (9 - ((q + 1) % 10));
                for (int p = tid; p < 512; p += 256) {
                    int i0 = ((p & ~(mt - 1)) << 1) | (p & (mt - 1)); // target bit = 0
                    if (i0 & mc) {
                        int i1 = i0 | mt;
                        float tr = sr[i0]; sr[i0] = sr[i1]; sr[i1] = tr;
                        float ti = si[i0]; si[i0] = si[i1]; si[i1] = ti;
                    }
                }
                __syncthreads();
            }
        }
        int wi = (layer == 3) ? 3 : layer;
        for (int q = 0; q < 10; ++q) {
            float c = wc[q * 4 + wi], s = wsn[q * 4 + wi];
            float u00r, u00i, u01r, u01i, u10r, u10i, u11r, u11i;
            if (layer == 0) {        // RX = [[c, -i s],[-i s, c]]
                u00r=c; u00i=0; u01r=0; u01i=-s; u10r=0; u10i=-s; u11r=c; u11i=0;
            } else if (layer == 2) { // RZ = [[e^{-it/2},0],[0,e^{+it/2}]]
                u00r=c; u00i=-s; u01r=0; u01i=0; u10r=0; u10i=0; u11r=c; u11i=s;
            } else {                 // RY = [[c,-s],[s,c]]
                u00r=c; u00i=0; u01r=-s; u01i=0; u10r=s; u10i=0; u11r=c; u11i=0;
            }
            int m = 1 << (9 - q);
            for (int p = tid; p < 512; p += 256) {
                int i0 = ((p & ~(m - 1)) << 1) | (p & (m - 1));
                int i1 = i0 | m;
                float ar = sr[i0], ai = si[i0], br = sr[i1], bi = si[i1];
                sr[i0] = u00r*ar - u00i*ai + u01r*br - u01i*bi;
                si[i0] = u00r*ai + u00i*ar + u01r*bi + u01i*br;
                sr[i1] = u10r*ar - u10i*ai + u11r*br - u11i*bi;
                si[i1] = u10r*ai + u10i*ar + u11r*bi + u11i*br;
            }
            __syncthreads();
        }
    }

    // QFT_MAT[j,k] = exp(+2*pi*i*j*k/1024)/32 -> radix-2 DIT FFT (+i twiddles)
    for (int i = tid; i < 1024; i += 256) {
        int r = (int)(__brev((unsigned)i) >> 22);
        if (r > i) {
            float tr = sr[i]; sr[i] = sr[r]; sr[r] = tr;
            float ti = si[i]; si[i] = si[r]; si[r] = ti;
        }
    }
    __syncthreads();
    for (int st = 1; st <= 10; ++st) {
        int hf = 1 << (st - 1);
        float astep = 6.28318530717958647f / (float)(1 << st);
        for (int p = tid; p < 512; p += 256) {
            int j2 = p & (hf - 1);
            int i0 = ((p >> (st - 1)) << st) | j2;
            int i1 = i0 + hf;
            float ang = astep * (float)j2;
            float sw, cw;
            __sincosf(ang, &sw, &cw);
            float br2 = sr[i1], bi2 = si[i1];
            float tr = cw*br2 - sw*bi2;
            float ti = cw*bi2 + sw*br2;
            float ur = sr[i0], ui = si[i0];
            sr[i0] = ur + tr; si[i0] = ui + ti;
            sr[i1] = ur - tr; si[i1] = ui - ti;
        }
        __syncthreads();
    }
    for (int k = tid; k < 1024; k += 256) {
        Wh[(size_t)jb * 2048 + 2*k]     = (_Float16)(sr[k] * 0.03125f);
        Wh[(size_t)jb * 2048 + 2*k + 1] = (_Float16)(si[k] * 0.03125f);
    }
}

// ---------------------------------------------------------------------------
// Kernel 1b: Bt[n][j] = Wh[j][n]   ([2048][1024] fp16, K-contiguous rows)
// ---------------------------------------------------------------------------
__global__ __launch_bounds__(256) void transpose_kernel(const _Float16* __restrict__ Wh,
                                                        _Float16* __restrict__ Bt)
{
    __shared__ _Float16 tile[32][33];
    const int bx = blockIdx.x;   // n tile (64)
    const int by = blockIdx.y;   // j tile (32)
    const int tx = threadIdx.x;  // 32
    const int ty = threadIdx.y;  // 8
    #pragma unroll
    for (int i = 0; i < 4; ++i) {
        int r = ty + 8*i;
        tile[r][tx] = Wh[(size_t)(by*32 + r) * 2048 + bx*32 + tx];
    }
    __syncthreads();
    #pragma unroll
    for (int i = 0; i < 4; ++i) {
        int r = ty + 8*i;
        Bt[(size_t)(bx*32 + r) * 1024 + by*32 + tx] = tile[tx][r];
    }
}

// ---------------------------------------------------------------------------
// Kernel 2: GEMM  Sh[8192][2048] = Xh[8192][1024] * Bt^T  (fp16 in, fp32 acc,
// fp16 out).  128x128 tile, BK=64 (16 k-iters), global_load_lds width 16,
// XOR-swizzled LDS (swizzle applied on the global-address side to keep the
// wave-uniform base + 16B*lane layout global_load_lds requires).
// ---------------------------------------------------------------------------
__global__ __launch_bounds__(256, 2) void gemm_kernel(const _Float16* __restrict__ A,
                                                      const _Float16* __restrict__ Bt,
                                                      _Float16* __restrict__ C)
{
    __shared__ __align__(16) _Float16 As[128][64];
    __shared__ __align__(16) _Float16 Bs[128][64];
    const int tid  = threadIdx.x;
    const int wave = tid >> 6;
    const int lane = tid & 63;
    const int m0 = blockIdx.y * 128;
    const int n0 = blockIdx.x * 128;

    // staging: wave w, instr t covers rows 32w+8t .. 32w+8t+7.
    // lane l -> row offset (l>>3), global k-chunk ((l&7) ^ (l>>3))  [swizzle]
    const int srow = lane >> 3;                 // 0..7
    const int schk = (lane & 7) ^ srow;         // swizzled chunk
    const _Float16* gA = A  + (size_t)(m0 + 32*wave + srow) * 1024 + schk * 8;
    const _Float16* gB = Bt + (size_t)(n0 + 32*wave + srow) * 1024 + schk * 8;
    _Float16* lA = &As[0][0] + wave*2048 + lane*8;
    _Float16* lB = &Bs[0][0] + wave*2048 + lane*8;

    // fragment indexing (verified layouts: A row=lane&15, k=(lane>>4)*8+j;
    // C/D col=lane&15, row=(lane>>4)*4+reg)
    const int fr = lane & 15;
    const int fc = lane >> 4;
    const int sx = fr & 7;          // de-swizzle constant for fragment reads
    const int wm = (wave >> 1) * 64;
    const int wn = (wave & 1) * 64;

    floatx4 acc[4][4];
    #pragma unroll
    for (int i = 0; i < 4; ++i)
        #pragma unroll
        for (int j = 0; j < 4; ++j)
            acc[i][j] = (floatx4){0.f, 0.f, 0.f, 0.f};

    for (int kt = 0; kt < 16; ++kt) {
        #pragma unroll
        for (int t = 0; t < 4; ++t) {
            __builtin_amdgcn_global_load_lds(GLB_CAST(gA + (size_t)t*8*1024), LDS_CAST(lA + t*512), 16, 0, 0);
            __builtin_amdgcn_global_load_lds(GLB_CAST(gB + (size_t)t*8*1024), LDS_CAST(lB + t*512), 16, 0, 0);
        }
        gA += 64; gB += 64;
        __syncthreads();
        #pragma unroll
        for (int kh = 0; kh < 2; ++kh) {
            half8_t af[4], bf[4];
            #pragma unroll
            for (int i = 0; i < 4; ++i)
                af[i] = *(const half8_t*)&As[wm + i*16 + fr][((kh*4 + fc) ^ sx) * 8];
            #pragma unroll
            for (int i = 0; i < 4; ++i)
                bf[i] = *(const half8_t*)&Bs[wn + i*16 + fr][((kh*4 + fc) ^ sx) * 8];
            #pragma unroll
            for (int mi = 0; mi < 4; ++mi)
                #pragma unroll
                for (int ni = 0; ni < 4; ++ni)
                    acc[mi][ni] = __builtin_amdgcn_mfma_f32_16x16x32_f16(af[mi], bf[ni], acc[mi][ni], 0, 0, 0);
        }
        __syncthreads();
    }

    #pragma unroll
    for (int mi = 0; mi < 4; ++mi) {
        #pragma unroll
        for (int r = 0; r < 4; ++r) {
            int row = m0 + wm + mi*16 + fc*4 + r;
            _Float16* cp = C + (size_t)row * 2048 + n0 + wn + fr;
            #pragma unroll
            for (int ni = 0; ni < 4; ++ni)
                cp[ni*16] = (_Float16)acc[mi][ni][r];
        }
    }
}

// ---------------------------------------------------------------------------
// 6-stage full-wave butterfly sum (all 64 lanes end with the total).
// ---------------------------------------------------------------------------
__device__ __forceinline__ float wred(float v) {
    v += __shfl_xor(v, 1);
    v += __shfl_xor(v, 2);
    v += __shfl_xor(v, 4);
    v += __shfl_xor(v, 8);
    v += __shfl_xor(v, 16);
    v += __shfl_xor(v, 32);
    return v;
}

// ---------------------------------------------------------------------------
// Kernel 3: expectations from S.  One WAVE per batch row; lane l owns the 16
// complex amps k = l*16 + i in registers.
//   k-bits 0..3  (qubits 9..6): intra-lane pairs, pure register math.
//   k-bits 4..9  (qubits 5..0): lane-XOR {1,2,4,8,16,32}; partner chunk
//     fetched from a 16B-XOR-swizzled wave-private LDS copy of the row.
//
// R4 restructure (post-mortem of R2/R3): rocprof showed VGPR_Count pinned at
// 52/64 with 110+ MB of scratch write traffic -- the effective VGPR cap for
// this 128-thread launch is ~64, and the 30-element cr/ci/cz accumulator
// arrays + c[16] exceeded it, so the kernel was spill-bound (185 MB HBM vs
// 34.5 MB ideal).  Fix: eliminate the accumulator arrays entirely.  Each
// qubit's per-lane (rr, ii, zz) values are wave-reduced IMMEDIATELY via a
// 6-stage shfl_xor butterfly and cndmask'ed into a single per-lane output
// register (lane o holds out[:,o]).  The LDS transpose + 60-lane serial
// reduction is gone too.  Peak live state: c[16] (32 VGPR) + P2s + temps
// ~= 50 VGPR -> fits under the cap with margin, zero scratch.
// ---------------------------------------------------------------------------
__global__ __launch_bounds__(128, 2) void expect_kernel(const _Float16* __restrict__ Sh,
                                                        float* __restrict__ out)
{
    __shared__ __align__(16) float buf[2][2048];   // per-wave row copy (512 float4)
    const int tid = threadIdx.x;
    const int w = tid >> 6, l = tid & 63;
    const int row = blockIdx.x * 2 + w;
    float* bw = buf[w];

    // ---- load own 16 complex amps (64B contiguous per lane) -> registers
    const _Float16* src = Sh + (size_t)row * 2048 + l * 32;
    float2 c[16];
    #pragma unroll
    for (int t = 0; t < 4; ++t) {
        half8_t v = ((const half8_t*)src)[t];
        #pragma unroll
        for (int u = 0; u < 4; ++u)
            c[t*4 + u] = make_float2((float)v[2*u], (float)v[2*u + 1]);
    }

    // ---- stage to swizzled LDS: unit j (2 complex) at slot l*8 + (j ^ (l&7))
    #pragma unroll
    for (int j = 0; j < 8; ++j) {
        int su = l*8 + (j ^ (l & 7));
        ((float4*)bw)[su] = make_float4(c[2*j].x, c[2*j].y, c[2*j+1].x, c[2*j+1].y);
    }

    float P2s = 0.f;
    #pragma unroll
    for (int i = 0; i < 16; ++i)
        P2s += c[i].x*c[i].x + c[i].y*c[i].y;

    float outv = 0.f;   // lane o ends up holding out[row][o]

    // ---- intra-lane qubits: k-bit p = 0..3  ->  q = 9-p
    #pragma unroll
    for (int p = 0; p < 4; ++p) {
        const int m = 1 << p;
        const int q = 9 - p;
        float rr = 0.f, ii = 0.f, zz = 0.f;
        #pragma unroll
        for (int i = 0; i < 16; ++i) {
            if (i & m) continue;
            const int j = i | m;
            rr += c[i].x*c[j].x + c[i].y*c[j].y;
            ii += c[i].x*c[j].y - c[i].y*c[j].x;
            zz += (c[i].x*c[i].x + c[i].y*c[i].y) - (c[j].x*c[j].x + c[j].y*c[j].y);
        }
        rr = wred(rr);
        ii = wred(ii);
        zz = wred(zz);
        outv = (l == q)      ? 2.f*rr : outv;
        outv = (l == 10 + q) ? 2.f*ii : outv;
        outv = (l == 20 + q) ? zz     : outv;
    }

    // ---- cross-lane qubits: lane-bit e (k-bit 4+e) -> q = 5-e
    // (wave-internal LDS ordering: no barrier needed)
    #pragma unroll
    for (int e = 0; e < 6; ++e) {
        const int q = 5 - e;
        const int part = l ^ (1 << e);
        const int mybit = (l >> e) & 1;
        const float sgn = mybit ? -1.f : 1.f;
        const int j0 = mybit ? 4 : 0;   // my half of the pair's units (LDS addr only)
        float rr = 0.f, ii = 0.f;
        #pragma unroll
        for (int j = 0; j < 4; ++j) {
            const int su = part*8 + ((j0 + j) ^ (part & 7));
            float4 f = ((const float4*)bw)[su];
            // own amps selected by VALUE so c[] indices stay compile-time.
            const float2 a0 = c[2*j],     a1 = c[2*j + 1];
            const float2 b0 = c[2*j + 8], b1 = c[2*j + 9];
            const float m0x = mybit ? b0.x : a0.x;
            const float m0y = mybit ? b0.y : a0.y;
            const float m1x = mybit ? b1.x : a1.x;
            const float m1y = mybit ? b1.y : a1.y;
            rr += m0x*f.x + m0y*f.y;
            ii += m0x*f.y - m0y*f.x;
            rr += m1x*f.z + m1y*f.w;
            ii += m1x*f.w - m1y*f.z;
        }
        float rr_s = wred(rr);
        float ii_s = wred(sgn * ii);
        float zz_s = wred(sgn * P2s);
        outv = (l == q)      ? 2.f*rr_s : outv;
        outv = (l == 10 + q) ? 2.f*ii_s : outv;
        outv = (l == 20 + q) ? zz_s     : outv;
    }

    if (l < 30)
        out[(size_t)row * 30 + l] = outv;
}

// ---------------------------------------------------------------------------
extern "C" void kernel_launch(void* const* d_in, const int* in_sizes, int n_in,
                              void* d_out, int out_size, void* d_ws, size_t ws_size,
                              hipStream_t stream) {
    const float* x = (const float*)d_in[0];   // [8192][1024]
    const float* w = (const float*)d_in[1];   // [10][4]
    float* out = (float*)d_out;               // [8192][30]
    char* ws = (char*)d_ws;
    // workspace layout (56 MB total):
    _Float16* Wh = (_Float16*)(ws);                         //  4 MB [1024][2048]
    _Float16* Bt = (_Float16*)(ws + ((size_t)4  << 20));    //  4 MB [2048][1024]
    _Float16* Xh = (_Float16*)(ws + ((size_t)8  << 20));    // 16 MB [8192][1024]
    _Float16* Sh = (_Float16*)(ws + ((size_t)24 << 20));    // 32 MB [8192][2048]

    prep_kernel<<<9216, 256, 0, stream>>>(w, x, Wh, Xh);
    transpose_kernel<<<dim3(64, 32), dim3(32, 8), 0, stream>>>(Wh, Bt);
    gemm_kernel<<<dim3(16, 64), 256, 0, stream>>>(Xh, Bt, Sh);
    expect_kernel<<<4096, 128, 0, stream>>>(Sh, out);
}

// Round 3
// 155.322 us; speedup vs baseline: 1.2826x; 1.1080x over previous
//
#include <hip/hip_runtime.h>

// ---------------------------------------------------------------------------
// QuantumQKGenerator: out[b, 0..9]=<X_q>, [10..19]=<Y_q>, [20..29]=<Z_q> of
// state S = QFT * U_circuit * normalize(x[b]).  Since x is real and the
// circuit+QFT is a fixed unitary W (depends only on the 40 weights), we:
//   1) prep: build W rows by basis-state sim + FFT  AND  normalize x -> fp16
//   2) transpose W to K-contiguous layout for MFMA
//   3) S = Xn @ W  as one fp16 MFMA GEMM  M=8192 N=2048(re/im) K=1024
//   4) expect: per-wave row reduction, butterfly wave-sums, minimal VGPR state
//
// R5 prep restructure (post-mortem R4: prep=45us top dispatch, VALUBusy 47%,
// 5.18M LDS conflict cycles, hbm 10% -> latency-bound on ~62 sync'd LDS
// stages/block):
//   - 2 gate-bits per phase (4-amp groups): 5 phases/layer, not 10
//   - CNOT ring (10 stages) + bit-reversal folded into ONE gather pass via
//     the composed basis-permutation; following RY layer runs on reversed
//     bit positions (wire q -> bit q)
//   - radix-4 FFT (2 radix-2 stages fused, i*w twiddle): 5 phases, not 10
//   - IDX(k)=k+(k>>5) pad to break power-of-2 bank conflicts
//   ~28 barriers vs ~62, gate LDS traffic halved.
// ---------------------------------------------------------------------------

typedef _Float16 half8_t __attribute__((ext_vector_type(8)));
typedef _Float16 half4_t __attribute__((ext_vector_type(4)));
typedef float floatx4 __attribute__((ext_vector_type(4)));

#define GLB_CAST(p) ((const __attribute__((address_space(1))) void*)(p))
#define LDS_CAST(p) ((__attribute__((address_space(3))) void*)(p))

#define IDX(k) ((k) + ((k) >> 5))   // pad 1 float per 32: max 1023 -> 1054

// apply 2x2 gate (type 0=RX, 1=RY, 2=RZ; c=cos(t/2), s=sin(t/2)) to pair
__device__ __forceinline__ void gate2(int type, float c, float s,
                                      float& ar, float& ai, float& br, float& bi)
{
    float nar, nai, nbr, nbi;
    if (type == 0) {        // RX = [[c,-is],[-is,c]]
        nar =  c*ar + s*bi;  nai =  c*ai - s*br;
        nbr =  s*ai + c*br;  nbi = -s*ar + c*bi;
    } else if (type == 2) { // RZ = diag(e^{-it/2}, e^{+it/2})
        nar =  c*ar + s*ai;  nai =  c*ai - s*ar;
        nbr =  c*br - s*bi;  nbi =  c*bi + s*br;
    } else {                // RY = [[c,-s],[s,c]]
        nar =  c*ar - s*br;  nai =  c*ai - s*bi;
        nbr =  s*ar + c*br;  nbi =  s*ai + c*bi;
    }
    ar = nar; ai = nai; br = nbr; bi = nbi;
}

// ---------------------------------------------------------------------------
// Kernel 1: blocks [0,1024): simulate circuit on basis |jb>, FFT, emit W row.
//           blocks [1024,9216): row-normalize x -> fp16 Xh.
// Wire q <-> bit position (9-q)  (wire 0 = MSB)  [pre-reversal layers].
// ---------------------------------------------------------------------------
__global__ __launch_bounds__(256) void prep_kernel(const float* __restrict__ w,
                                                   const float* __restrict__ x,
                                                   _Float16* __restrict__ Wh,
                                                   _Float16* __restrict__ Xh)
{
    __shared__ float smem[4304];   // sr[1056] si[1056] sr2[1056] si2[1056] wc[40] wsn[40]
    const int tid = threadIdx.x;

    if (blockIdx.x >= 1024) {
        // ---------------- normalize path ----------------
        float* wsum = smem;
        const int b = blockIdx.x - 1024;
        float4 v = ((const float4*)(x + (size_t)b * 1024))[tid];
        float ss = v.x*v.x + v.y*v.y + v.z*v.z + v.w*v.w;
        #pragma unroll
        for (int off = 32; off; off >>= 1) ss += __shfl_down(ss, off);
        if ((tid & 63) == 0) wsum[tid >> 6] = ss;
        __syncthreads();
        float scale = 1.0f / fmaxf(sqrtf(wsum[0] + wsum[1] + wsum[2] + wsum[3]), 1e-8f);
        half4_t h;
        h[0] = (_Float16)(v.x * scale);
        h[1] = (_Float16)(v.y * scale);
        h[2] = (_Float16)(v.z * scale);
        h[3] = (_Float16)(v.w * scale);
        ((half4_t*)(Xh + (size_t)b * 1024))[tid] = h;
        return;
    }

    // ---------------- build_w path ----------------
    float* sr  = smem;
    float* si  = smem + 1056;
    float* sr2 = smem + 2112;
    float* si2 = smem + 3168;
    float* wc  = smem + 4224;
    float* wsn = smem + 4264;
    const int jb = blockIdx.x;

    if (tid < 40) {
        float t = w[tid] * 0.5f;
        wc[tid]  = cosf(t);
        wsn[tid] = sinf(t);
    }
    #pragma unroll
    for (int u = 0; u < 4; ++u) {
        int k = tid + 256*u;
        sr[IDX(k)] = (k == jb) ? 1.0f : 0.0f;
        si[IDX(k)] = 0.0f;
    }
    __syncthreads();

    // ---- layers 0..2 (RX, RY, RZ), un-reversed bits: bit p <-> wire 9-p.
    // 2 bits per phase: thread owns 4-amp group {base, +m1, +m2, +m1+m2}.
    for (int layer = 0; layer < 3; ++layer) {
        for (int pp = 0; pp < 5; ++pp) {
            const int p  = 2*pp;
            const int m1 = 1 << p, m2 = 2 << p;
            const int base = ((tid >> p) << (p + 2)) | (tid & (m1 - 1));
            const int iA = IDX(base), iB = IDX(base + m1);
            const int iC = IDX(base + m2), iD = IDX(base + m1 + m2);
            float Ar = sr[iA], Ai = si[iA], Br = sr[iB], Bi = si[iB];
            float Cr = sr[iC], Ci = si[iC], Dr = sr[iD], Di = si[iD];
            // gate on bit p (wire 9-p): pairs (A,B), (C,D)
            {
                float c = wc[(9 - p)*4 + layer], s = wsn[(9 - p)*4 + layer];
                gate2(layer, c, s, Ar, Ai, Br, Bi);
                gate2(layer, c, s, Cr, Ci, Dr, Di);
            }
            // gate on bit p+1 (wire 8-p): pairs (A,C), (B,D)
            {
                float c = wc[(8 - p)*4 + layer], s = wsn[(8 - p)*4 + layer];
                gate2(layer, c, s, Ar, Ai, Cr, Ci);
                gate2(layer, c, s, Br, Bi, Dr, Di);
            }
            sr[iA] = Ar; si[iA] = Ai; sr[iB] = Br; si[iB] = Bi;
            sr[iC] = Cr; si[iC] = Ci; sr[iD] = Dr; si[iD] = Di;
            __syncthreads();
        }
    }

    // ---- CNOT ring + bit-reversal as ONE gather: new[k] = old[sigma(rev(k))]
    // sigma = C_{q=0} o C_{q=1} o ... o C_{q=9}  (first-applied outermost),
    // C_q flips bit pt when bit pc is set (pc=9-q, pt=8-q; q=9: pc=0, pt=9).
    #pragma unroll
    for (int u = 0; u < 4; ++u) {
        int k = tid + 256*u;
        int m = (int)(__brev((unsigned)k) >> 22);
        #pragma unroll
        for (int q = 9; q >= 0; --q) {
            const int pc = (q == 9) ? 0 : 9 - q;
            const int pt = (q == 9) ? 9 : 8 - q;
            m ^= ((m >> pc) & 1) << pt;
        }
        sr2[IDX(k)] = sr[IDX(m)];
        si2[IDX(k)] = si[IDX(m)];
    }
    __syncthreads();

    // ---- layer 3 (RY) on REVERSED bits: bit p <-> wire p.
    // phase 0 reads the gather buffer (sr2/si2) and writes sr/si.
    for (int pp = 0; pp < 5; ++pp) {
        const int p  = 2*pp;
        const int m1 = 1 << p, m2 = 2 << p;
        const int base = ((tid >> p) << (p + 2)) | (tid & (m1 - 1));
        const int iA = IDX(base), iB = IDX(base + m1);
        const int iC = IDX(base + m2), iD = IDX(base + m1 + m2);
        const float* rsrc = (pp == 0) ? sr2 : sr;
        const float* isrc = (pp == 0) ? si2 : si;
        float Ar = rsrc[iA], Ai = isrc[iA], Br = rsrc[iB], Bi = isrc[iB];
        float Cr = rsrc[iC], Ci = isrc[iC], Dr = rsrc[iD], Di = isrc[iD];
        {
            float c = wc[p*4 + 3], s = wsn[p*4 + 3];        // wire p on bit p
            gate2(1, c, s, Ar, Ai, Br, Bi);
            gate2(1, c, s, Cr, Ci, Dr, Di);
        }
        {
            float c = wc[(p + 1)*4 + 3], s = wsn[(p + 1)*4 + 3];  // wire p+1
            gate2(1, c, s, Ar, Ai, Cr, Ci);
            gate2(1, c, s, Br, Bi, Dr, Di);
        }
        sr[iA] = Ar; si[iA] = Ai; sr[iB] = Br; si[iB] = Bi;
        sr[iC] = Cr; si[iC] = Ci; sr[iD] = Dr; si[iD] = Di;
        __syncthreads();
    }

    // ---- FFT (positive sign, input already bit-reversed): 5 fused
    // radix-2-pair phases.  Stage st pairs dist hf, stage st+1 dist 2hf;
    // odd-pair twiddle is i*w2 (positive convention).
    for (int sp = 0; sp < 5; ++sp) {
        const int st = 2*sp + 1;
        const int hf = 1 << (st - 1);
        const int j2 = tid & (hf - 1);
        const int i0 = ((tid >> (st - 1)) << (st + 1)) | j2;
        const int iA = IDX(i0), iB = IDX(i0 + hf);
        const int iC = IDX(i0 + 2*hf), iD = IDX(i0 + 3*hf);
        float Ar = sr[iA], Ai = si[iA], Br = sr[iB], Bi = si[iB];
        float Cr = sr[iC], Ci = si[iC], Dr = sr[iD], Di = si[iD];
        const float th1 = (6.28318530717958647f / (float)(1 << st)) * (float)j2;
        float s1, c1, s2, c2;
        __sincosf(th1, &s1, &c1);
        __sincosf(th1 * 0.5f, &s2, &c2);
        // stage st
        float t1r = c1*Br - s1*Bi, t1i = c1*Bi + s1*Br;
        float Apr = Ar + t1r, Api = Ai + t1i;
        float Bpr = Ar - t1r, Bpi = Ai - t1i;
        float t2r = c1*Dr - s1*Di, t2i = c1*Di + s1*Dr;
        float Cpr = Cr + t2r, Cpi = Ci + t2i;
        float Dpr = Cr - t2r, Dpi = Ci - t2i;
        // stage st+1
        float u1r = c2*Cpr - s2*Cpi, u1i = c2*Cpi + s2*Cpr;
        sr[iA] = Apr + u1r; si[iA] = Api + u1i;
        sr[iC] = Apr - u1r; si[iC] = Api - u1i;
        float u2r = c2*Dpr - s2*Dpi, u2i = c2*Dpi + s2*Dpr;
        sr[iB] = Bpr - u2i; si[iB] = Bpi + u2r;   // B' + i*u2
        sr[iD] = Bpr + u2i; si[iD] = Bpi - u2r;   // B' - i*u2
        __syncthreads();
    }

    // ---- emit W row, vectorized 16B stores (thread t -> amps 4t..4t+3)
    half8_t v;
    #pragma unroll
    for (int u = 0; u < 4; ++u) {
        const int k = 4*tid + u;
        v[2*u]     = (_Float16)(sr[IDX(k)] * 0.03125f);
        v[2*u + 1] = (_Float16)(si[IDX(k)] * 0.03125f);
    }
    ((half8_t*)(Wh + (size_t)jb * 2048))[tid] = v;
}

// ---------------------------------------------------------------------------
// Kernel 1b: Bt[n][j] = Wh[j][n]   ([2048][1024] fp16, K-contiguous rows)
// ---------------------------------------------------------------------------
__global__ __launch_bounds__(256) void transpose_kernel(const _Float16* __restrict__ Wh,
                                                        _Float16* __restrict__ Bt)
{
    __shared__ _Float16 tile[32][33];
    const int bx = blockIdx.x;   // n tile (64)
    const int by = blockIdx.y;   // j tile (32)
    const int tx = threadIdx.x;  // 32
    const int ty = threadIdx.y;  // 8
    #pragma unroll
    for (int i = 0; i < 4; ++i) {
        int r = ty + 8*i;
        tile[r][tx] = Wh[(size_t)(by*32 + r) * 2048 + bx*32 + tx];
    }
    __syncthreads();
    #pragma unroll
    for (int i = 0; i < 4; ++i) {
        int r = ty + 8*i;
        Bt[(size_t)(bx*32 + r) * 1024 + by*32 + tx] = tile[tx][r];
    }
}

// ---------------------------------------------------------------------------
// Kernel 2: GEMM  Sh[8192][2048] = Xh[8192][1024] * Bt^T  (fp16 in, fp32 acc,
// fp16 out).  128x128 tile, BK=64 (16 k-iters), global_load_lds width 16,
// XOR-swizzled LDS (swizzle applied on the global-address side to keep the
// wave-uniform base + 16B*lane layout global_load_lds requires).
// ---------------------------------------------------------------------------
__global__ __launch_bounds__(256, 2) void gemm_kernel(const _Float16* __restrict__ A,
                                                      const _Float16* __restrict__ Bt,
                                                      _Float16* __restrict__ C)
{
    __shared__ __align__(16) _Float16 As[128][64];
    __shared__ __align__(16) _Float16 Bs[128][64];
    const int tid  = threadIdx.x;
    const int wave = tid >> 6;
    const int lane = tid & 63;
    const int m0 = blockIdx.y * 128;
    const int n0 = blockIdx.x * 128;

    // staging: wave w, instr t covers rows 32w+8t .. 32w+8t+7.
    // lane l -> row offset (l>>3), global k-chunk ((l&7) ^ (l>>3))  [swizzle]
    const int srow = lane >> 3;                 // 0..7
    const int schk = (lane & 7) ^ srow;         // swizzled chunk
    const _Float16* gA = A  + (size_t)(m0 + 32*wave + srow) * 1024 + schk * 8;
    const _Float16* gB = Bt + (size_t)(n0 + 32*wave + srow) * 1024 + schk * 8;
    _Float16* lA = &As[0][0] + wave*2048 + lane*8;
    _Float16* lB = &Bs[0][0] + wave*2048 + lane*8;

    // fragment indexing (verified layouts: A row=lane&15, k=(lane>>4)*8+j;
    // C/D col=lane&15, row=(lane>>4)*4+reg)
    const int fr = lane & 15;
    const int fc = lane >> 4;
    const int sx = fr & 7;          // de-swizzle constant for fragment reads
    const int wm = (wave >> 1) * 64;
    const int wn = (wave & 1) * 64;

    floatx4 acc[4][4];
    #pragma unroll
    for (int i = 0; i < 4; ++i)
        #pragma unroll
        for (int j = 0; j < 4; ++j)
            acc[i][j] = (floatx4){0.f, 0.f, 0.f, 0.f};

    for (int kt = 0; kt < 16; ++kt) {
        #pragma unroll
        for (int t = 0; t < 4; ++t) {
            __builtin_amdgcn_global_load_lds(GLB_CAST(gA + (size_t)t*8*1024), LDS_CAST(lA + t*512), 16, 0, 0);
            __builtin_amdgcn_global_load_lds(GLB_CAST(gB + (size_t)t*8*1024), LDS_CAST(lB + t*512), 16, 0, 0);
        }
        gA += 64; gB += 64;
        __syncthreads();
        #pragma unroll
        for (int kh = 0; kh < 2; ++kh) {
            half8_t af[4], bf[4];
            #pragma unroll
            for (int i = 0; i < 4; ++i)
                af[i] = *(const half8_t*)&As[wm + i*16 + fr][((kh*4 + fc) ^ sx) * 8];
            #pragma unroll
            for (int i = 0; i < 4; ++i)
                bf[i] = *(const half8_t*)&Bs[wn + i*16 + fr][((kh*4 + fc) ^ sx) * 8];
            #pragma unroll
            for (int mi = 0; mi < 4; ++mi)
                #pragma unroll
                for (int ni = 0; ni < 4; ++ni)
                    acc[mi][ni] = __builtin_amdgcn_mfma_f32_16x16x32_f16(af[mi], bf[ni], acc[mi][ni], 0, 0, 0);
        }
        __syncthreads();
    }

    #pragma unroll
    for (int mi = 0; mi < 4; ++mi) {
        #pragma unroll
        for (int r = 0; r < 4; ++r) {
            int row = m0 + wm + mi*16 + fc*4 + r;
            _Float16* cp = C + (size_t)row * 2048 + n0 + wn + fr;
            #pragma unroll
            for (int ni = 0; ni < 4; ++ni)
                cp[ni*16] = (_Float16)acc[mi][ni][r];
        }
    }
}

// ---------------------------------------------------------------------------
// 6-stage full-wave butterfly sum (all 64 lanes end with the total).
// ---------------------------------------------------------------------------
__device__ __forceinline__ float wred(float v) {
    v += __shfl_xor(v, 1);
    v += __shfl_xor(v, 2);
    v += __shfl_xor(v, 4);
    v += __shfl_xor(v, 8);
    v += __shfl_xor(v, 16);
    v += __shfl_xor(v, 32);
    return v;
}

// ---------------------------------------------------------------------------
// Kernel 3: expectations from S.  One WAVE per batch row; lane l owns the 16
// complex amps k = l*16 + i in registers.  Per qubit the (rr,ii,zz) values
// are wave-reduced immediately (shfl_xor butterfly) and cndmask'ed into one
// per-lane output register -- peak live state ~50 VGPR, zero scratch.
// ---------------------------------------------------------------------------
__global__ __launch_bounds__(128, 2) void expect_kernel(const _Float16* __restrict__ Sh,
                                                        float* __restrict__ out)
{
    __shared__ __align__(16) float buf[2][2048];   // per-wave row copy (512 float4)
    const int tid = threadIdx.x;
    const int w = tid >> 6, l = tid & 63;
    const int row = blockIdx.x * 2 + w;
    float* bw = buf[w];

    // ---- load own 16 complex amps (64B contiguous per lane) -> registers
    const _Float16* src = Sh + (size_t)row * 2048 + l * 32;
    float2 c[16];
    #pragma unroll
    for (int t = 0; t < 4; ++t) {
        half8_t v = ((const half8_t*)src)[t];
        #pragma unroll
        for (int u = 0; u < 4; ++u)
            c[t*4 + u] = make_float2((float)v[2*u], (float)v[2*u + 1]);
    }

    // ---- stage to swizzled LDS: unit j (2 complex) at slot l*8 + (j ^ (l&7))
    #pragma unroll
    for (int j = 0; j < 8; ++j) {
        int su = l*8 + (j ^ (l & 7));
        ((float4*)bw)[su] = make_float4(c[2*j].x, c[2*j].y, c[2*j+1].x, c[2*j+1].y);
    }

    float P2s = 0.f;
    #pragma unroll
    for (int i = 0; i < 16; ++i)
        P2s += c[i].x*c[i].x + c[i].y*c[i].y;

    float outv = 0.f;   // lane o ends up holding out[row][o]

    // ---- intra-lane qubits: k-bit p = 0..3  ->  q = 9-p
    #pragma unroll
    for (int p = 0; p < 4; ++p) {
        const int m = 1 << p;
        const int q = 9 - p;
        float rr = 0.f, ii = 0.f, zz = 0.f;
        #pragma unroll
        for (int i = 0; i < 16; ++i) {
            if (i & m) continue;
            const int j = i | m;
            rr += c[i].x*c[j].x + c[i].y*c[j].y;
            ii += c[i].x*c[j].y - c[i].y*c[j].x;
            zz += (c[i].x*c[i].x + c[i].y*c[i].y) - (c[j].x*c[j].x + c[j].y*c[j].y);
        }
        rr = wred(rr);
        ii = wred(ii);
        zz = wred(zz);
        outv = (l == q)      ? 2.f*rr : outv;
        outv = (l == 10 + q) ? 2.f*ii : outv;
        outv = (l == 20 + q) ? zz     : outv;
    }

    // ---- cross-lane qubits: lane-bit e (k-bit 4+e) -> q = 5-e
    // (wave-internal LDS ordering: no barrier needed)
    #pragma unroll
    for (int e = 0; e < 6; ++e) {
        const int q = 5 - e;
        const int part = l ^ (1 << e);
        const int mybit = (l >> e) & 1;
        const float sgn = mybit ? -1.f : 1.f;
        const int j0 = mybit ? 4 : 0;   // my half of the pair's units (LDS addr only)
        float rr = 0.f, ii = 0.f;
        #pragma unroll
        for (int j = 0; j < 4; ++j) {
            const int su = part*8 + ((j0 + j) ^ (part & 7));
            float4 f = ((const float4*)bw)[su];
            // own amps selected by VALUE so c[] indices stay compile-time.
            const float2 a0 = c[2*j],     a1 = c[2*j + 1];
            const float2 b0 = c[2*j + 8], b1 = c[2*j + 9];
            const float m0x = mybit ? b0.x : a0.x;
            const float m0y = mybit ? b0.y : a0.y;
            const float m1x = mybit ? b1.x : a1.x;
            const float m1y = mybit ? b1.y : a1.y;
            rr += m0x*f.x + m0y*f.y;
            ii += m0x*f.y - m0y*f.x;
            rr += m1x*f.z + m1y*f.w;
            ii += m1x*f.w - m1y*f.z;
        }
        float rr_s = wred(rr);
        float ii_s = wred(sgn * ii);
        float zz_s = wred(sgn * P2s);
        outv = (l == q)      ? 2.f*rr_s : outv;
        outv = (l == 10 + q) ? 2.f*ii_s : outv;
        outv = (l == 20 + q) ? zz_s     : outv;
    }

    if (l < 30)
        out[(size_t)row * 30 + l] = outv;
}

// ---------------------------------------------------------------------------
extern "C" void kernel_launch(void* const* d_in, const int* in_sizes, int n_in,
                              void* d_out, int out_size, void* d_ws, size_t ws_size,
                              hipStream_t stream) {
    const float* x = (const float*)d_in[0];   // [8192][1024]
    const float* w = (const float*)d_in[1];   // [10][4]
    float* out = (float*)d_out;               // [8192][30]
    char* ws = (char*)d_ws;
    // workspace layout (56 MB total):
    _Float16* Wh = (_Float16*)(ws);                         //  4 MB [1024][2048]
    _Float16* Bt = (_Float16*)(ws + ((size_t)4  << 20));    //  4 MB [2048][1024]
    _Float16* Xh = (_Float16*)(ws + ((size_t)8  << 20));    // 16 MB [8192][1024]
    _Float16* Sh = (_Float16*)(ws + ((size_t)24 << 20));    // 32 MB [8192][2048]

    prep_kernel<<<9216, 256, 0, stream>>>(w, x, Wh, Xh);
    transpose_kernel<<<dim3(64, 32), dim3(32, 8), 0, stream>>>(Wh, Bt);
    gemm_kernel<<<dim3(16, 64), 256, 0, stream>>>(Xh, Bt, Sh);
    expect_kernel<<<4096, 128, 0, stream>>>(Sh, out);
}